// Round 2
// baseline (174.686 us; speedup 1.0000x reference)
//
#include <hip/hip_runtime.h>

// LoReFT intervention: B=8, S=4096, D=3072, RANK=16, P=64. All tensors fp32.
// out = h everywhere; rows [b, positions[p], :] get h + (h·(W_w-R_w)^T + W_b)·R_w.

constexpr int S_DIM   = 4096;
constexpr int D_DIM   = 3072;
constexpr int RANK    = 16;
constexpr int THREADS = 256;
constexpr int CHUNKS  = D_DIM / 4;        // 768 float4 chunks per row
constexpr int ITERS   = CHUNKS / THREADS; // 3

__global__ __launch_bounds__(THREADS) void loreft_rows(
    const float* __restrict__ h,
    const float* __restrict__ Rw,
    const float* __restrict__ Ww,
    const float* __restrict__ Wb,
    const void*  __restrict__ posraw,
    float*       __restrict__ out,
    int P)
{
    const int b = blockIdx.x / P;
    const int p = blockIdx.x - b * P;

    // positions may be int32 or int64 on device. For this problem positions is
    // arange(P): as int64 (LE) the second 32-bit word is the high half of
    // elem 0 (== 0); as int32 it is elem 1 (== 1). Uniform branch, all blocks agree.
    const int* p32 = (const int*)posraw;
    int s;
    if (P >= 2 && p32[1] == 0) {
        s = (int)(((const long long*)posraw)[p]);
    } else {
        s = p32[p];
    }

    const size_t rowbase = ((size_t)b * S_DIM + (size_t)s) * (size_t)D_DIM;

    const float4* __restrict__ h4 = reinterpret_cast<const float4*>(h + rowbase);
    const float4* __restrict__ w4 = reinterpret_cast<const float4*>(Ww);
    const float4* __restrict__ r4 = reinterpret_cast<const float4*>(Rw);

    const int tid = threadIdx.x;

    float partial[RANK];
    #pragma unroll
    for (int r = 0; r < RANK; ++r) partial[r] = 0.f;

    float4 hv[ITERS];

    // Pass 1: diff[r] = sum_d h[d] * (Ww[r,d] - Rw[r,d])
    #pragma unroll
    for (int it = 0; it < ITERS; ++it) {
        const int c = tid + it * THREADS;
        const float4 a = h4[c];
        hv[it] = a;
        #pragma unroll
        for (int r = 0; r < RANK; ++r) {
            const float4 w = w4[r * CHUNKS + c];
            const float4 rr = r4[r * CHUNKS + c];
            partial[r] += a.x * (w.x - rr.x)
                        + a.y * (w.y - rr.y)
                        + a.z * (w.z - rr.z)
                        + a.w * (w.w - rr.w);
        }
    }

    // Wave-64 shuffle reduce, then cross-wave reduce via LDS
    #pragma unroll
    for (int r = 0; r < RANK; ++r) {
        float v = partial[r];
        #pragma unroll
        for (int off = 32; off > 0; off >>= 1)
            v += __shfl_down(v, off, 64);
        partial[r] = v;
    }

    __shared__ float red[RANK][4];
    __shared__ float diff[RANK];
    const int lane = tid & 63;
    const int wave = tid >> 6;
    if (lane == 0) {
        #pragma unroll
        for (int r = 0; r < RANK; ++r) red[r][wave] = partial[r];
    }
    __syncthreads();
    if (tid < RANK) {
        diff[tid] = red[tid][0] + red[tid][1] + red[tid][2] + red[tid][3]
                  + Wb[tid];
    }
    __syncthreads();

    float dl[RANK];
    #pragma unroll
    for (int r = 0; r < RANK; ++r) dl[r] = diff[r];

    // Pass 2: out[d] = h[d] + sum_r diff[r] * Rw[r,d]
    float4* __restrict__ o4 = reinterpret_cast<float4*>(out + rowbase);
    #pragma unroll
    for (int it = 0; it < ITERS; ++it) {
        const int c = tid + it * THREADS;
        float4 a = hv[it];
        #pragma unroll
        for (int r = 0; r < RANK; ++r) {
            const float4 rr = r4[r * CHUNKS + c];
            const float d = dl[r];
            a.x += d * rr.x;
            a.y += d * rr.y;
            a.z += d * rr.z;
            a.w += d * rr.w;
        }
        o4[c] = a;
    }
}

extern "C" void kernel_launch(void* const* d_in, const int* in_sizes, int n_in,
                              void* d_out, int out_size, void* d_ws, size_t ws_size,
                              hipStream_t stream)
{
    const float* h   = (const float*)d_in[0];
    const float* Rw  = (const float*)d_in[1];
    const float* Ww  = (const float*)d_in[2];
    const float* Wb  = (const float*)d_in[3];
    const void*  pos = d_in[4];
    float*       out = (float*)d_out;

    const int P = in_sizes[4];
    const int B = in_sizes[0] / (S_DIM * D_DIM);

    // Bulk identity copy h -> out (fp32). This is the memory-bound floor:
    // 2 x 402.7 MB of HBM traffic.
    hipMemcpyAsync(d_out, (const void*)h,
                   (size_t)in_sizes[0] * sizeof(float),
                   hipMemcpyDeviceToDevice, stream);

    // Fix up the B*P intervened rows (overwrites the copied values).
    loreft_rows<<<B * P, THREADS, 0, stream>>>(h, Rw, Ww, Wb, pos, out, P);
}

// Round 4
// 132.580 us; speedup vs baseline: 1.3176x; 1.3176x over previous
//
#include <hip/hip_runtime.h>

// LoReFT intervention: B=8, S=4096, D=3072, RANK=16, P=64. All tensors fp32.
// out = h everywhere; rows [b, positions[p], :] get h + (h·(W_w-R_w)^T + W_b)·R_w.
// Fused single kernel: one block per (b,s) row. Non-intervened rows stream-copy
// (nontemporal); intervened rows (s in positions) compute the rank-16 update.

constexpr int S_DIM   = 4096;
constexpr int D_DIM   = 3072;
constexpr int RANK    = 16;
constexpr int THREADS = 256;
constexpr int CHUNKS  = D_DIM / 4;        // 768 float4 chunks per row
constexpr int ITERS   = CHUNKS / THREADS; // 3

typedef float f32x4 __attribute__((ext_vector_type(4)));

__global__ __launch_bounds__(THREADS) void loreft_fused(
    const float* __restrict__ h,
    const float* __restrict__ Rw,
    const float* __restrict__ Ww,
    const float* __restrict__ Wb,
    const void*  __restrict__ posraw,
    float*       __restrict__ out,
    int P)
{
    const int row = blockIdx.x;           // = b*S_DIM + s
    const int s   = row & (S_DIM - 1);
    const int tid = threadIdx.x;

    // positions may be int64 or int32 on device. For arange data: as int64 (LE)
    // the 2nd 32-bit word is the high half of elem 0 (== 0); as int32 it is
    // elem 1 (== 1). Uniform branch; all blocks agree.
    const int*       p32 = (const int*)posraw;
    const long long* p64 = (const long long*)posraw;
    const bool is64 = (P >= 2 && p32[1] == 0);

    __shared__ int hit;
    if (tid == 0) hit = 0;
    __syncthreads();
    if (tid < P) {
        const int pv = is64 ? (int)p64[tid] : p32[tid];
        if (pv == s) hit = 1;   // benign same-value race
    }
    __syncthreads();

    const size_t rowbase = (size_t)row * (size_t)D_DIM;

    if (!hit) {
        // Streaming copy path: 3 x 16B per thread, nontemporal (no reuse).
        const f32x4* __restrict__ hv4 = reinterpret_cast<const f32x4*>(h + rowbase);
        f32x4*       __restrict__ ov4 = reinterpret_cast<f32x4*>(out + rowbase);
        f32x4 a0 = __builtin_nontemporal_load(&hv4[tid]);
        f32x4 a1 = __builtin_nontemporal_load(&hv4[tid + THREADS]);
        f32x4 a2 = __builtin_nontemporal_load(&hv4[tid + 2 * THREADS]);
        __builtin_nontemporal_store(a0, &ov4[tid]);
        __builtin_nontemporal_store(a1, &ov4[tid + THREADS]);
        __builtin_nontemporal_store(a2, &ov4[tid + 2 * THREADS]);
        return;
    }

    // ---- Intervened row: two-pass rank-16 update (validated round 2) ----
    const float4* __restrict__ h4 = reinterpret_cast<const float4*>(h + rowbase);
    float4*       __restrict__ o4 = reinterpret_cast<float4*>(out + rowbase);
    const float4* __restrict__ w4 = reinterpret_cast<const float4*>(Ww);
    const float4* __restrict__ r4 = reinterpret_cast<const float4*>(Rw);

    float partial[RANK];
    #pragma unroll
    for (int r = 0; r < RANK; ++r) partial[r] = 0.f;

    float4 hv[ITERS];

    // Pass 1: diff[r] = sum_d h[d] * (Ww[r,d] - Rw[r,d])
    #pragma unroll
    for (int it = 0; it < ITERS; ++it) {
        const int c = tid + it * THREADS;
        const float4 a = h4[c];
        hv[it] = a;
        #pragma unroll
        for (int r = 0; r < RANK; ++r) {
            const float4 w  = w4[r * CHUNKS + c];
            const float4 rr = r4[r * CHUNKS + c];
            partial[r] += a.x * (w.x - rr.x)
                        + a.y * (w.y - rr.y)
                        + a.z * (w.z - rr.z)
                        + a.w * (w.w - rr.w);
        }
    }

    // Wave-64 shuffle reduce, then cross-wave reduce via LDS
    #pragma unroll
    for (int r = 0; r < RANK; ++r) {
        float v = partial[r];
        #pragma unroll
        for (int off = 32; off > 0; off >>= 1)
            v += __shfl_down(v, off, 64);
        partial[r] = v;
    }

    __shared__ float red[RANK][4];
    __shared__ float diff[RANK];
    const int lane = tid & 63;
    const int wave = tid >> 6;
    if (lane == 0) {
        #pragma unroll
        for (int r = 0; r < RANK; ++r) red[r][wave] = partial[r];
    }
    __syncthreads();
    if (tid < RANK) {
        diff[tid] = red[tid][0] + red[tid][1] + red[tid][2] + red[tid][3]
                  + Wb[tid];
    }
    __syncthreads();

    float dl[RANK];
    #pragma unroll
    for (int r = 0; r < RANK; ++r) dl[r] = diff[r];

    // Pass 2: out[d] = h[d] + sum_r diff[r] * Rw[r,d]
    #pragma unroll
    for (int it = 0; it < ITERS; ++it) {
        const int c = tid + it * THREADS;
        float4 a = hv[it];
        #pragma unroll
        for (int r = 0; r < RANK; ++r) {
            const float4 rr = r4[r * CHUNKS + c];
            const float d = dl[r];
            a.x += d * rr.x;
            a.y += d * rr.y;
            a.z += d * rr.z;
            a.w += d * rr.w;
        }
        o4[c] = a;
    }
}

extern "C" void kernel_launch(void* const* d_in, const int* in_sizes, int n_in,
                              void* d_out, int out_size, void* d_ws, size_t ws_size,
                              hipStream_t stream)
{
    const float* h   = (const float*)d_in[0];
    const float* Rw  = (const float*)d_in[1];
    const float* Ww  = (const float*)d_in[2];
    const float* Wb  = (const float*)d_in[3];
    const void*  pos = d_in[4];
    float*       out = (float*)d_out;

    const int P = in_sizes[4];
    const int B = in_sizes[0] / (S_DIM * D_DIM);

    loreft_fused<<<B * S_DIM, THREADS, 0, stream>>>(h, Rw, Ww, Wb, pos, out, P);
}